// Round 1
// baseline (15897.066 us; speedup 1.0000x reference)
//
#include <hip/hip_runtime.h>

// Problem constants (reference: T=512, N=256, H=256, HR=64, WC=128, V=64)
#define TSTEPS 512
#define NBATCH 256
#define HID    256
#define TCHUNK 64
#define NCHUNK 8

typedef __attribute__((ext_vector_type(8))) short bf16x8;
typedef __attribute__((ext_vector_type(4))) float f32x4;

__device__ __forceinline__ unsigned short f2b(float x) {
    union { float f; unsigned int u; } c; c.f = x;
    unsigned int u = c.u;
    return (unsigned short)((u + 0x7fffu + ((u >> 16) & 1u)) >> 16);
}
__device__ __forceinline__ float sigmoidf_(float x) { return 1.f / (1.f + __expf(-x)); }
__device__ __forceinline__ float tanhf_(float x)    { return 1.f - 2.f / (1.f + __expf(2.f * x)); }

// ---------------------------------------------------------------------------
// Generic GEMM: C[M,N] = act(A[M,K] @ B + bias), bf16 MFMA, fp32 in/out.
// A row-major (lda). B row-major (K,N) (ldb) or, if TRANS_B, (N,K) row-major.
// Batched via blockIdx.z with element strides sA/sB/sC.
// Requires M%64==0, N%64==0, K%32==0.
// ---------------------------------------------------------------------------
template<bool TRANS_B, int ACT>
__global__ __launch_bounds__(256) void gemm_f32(
    const float* __restrict__ A, long lda, long sA,
    const float* __restrict__ B, long ldb, long sB,
    const float* __restrict__ bias,
    float* __restrict__ C, long ldc, long sC,
    int M, int N, int K)
{
    __shared__ __align__(16) unsigned short As[64][32];  // [m][k] bf16
    __shared__ __align__(16) unsigned short Bs[64][32];  // [n][k] bf16
    const int z = blockIdx.z;
    A += (long)z * sA; B += (long)z * sB; C += (long)z * sC;
    const int n0 = blockIdx.x * 64, m0 = blockIdx.y * 64;
    const int tid  = threadIdx.x;
    const int lane = tid & 63, w = tid >> 6;
    const int wr = (w >> 1) * 32, wc = (w & 1) * 32;

    f32x4 acc[2][2];
#pragma unroll
    for (int i = 0; i < 2; i++)
#pragma unroll
        for (int j = 0; j < 2; j++) acc[i][j] = (f32x4){0.f, 0.f, 0.f, 0.f};

    for (int k0 = 0; k0 < K; k0 += 32) {
        {   // stage A tile: 64 rows x 32 k
            const int r = tid >> 2, ck = (tid & 3) << 3;
            const float* s = A + (long)(m0 + r) * lda + k0 + ck;
            float4 v0 = *(const float4*)s, v1 = *(const float4*)(s + 4);
            unsigned short* d = &As[r][ck];
            d[0] = f2b(v0.x); d[1] = f2b(v0.y); d[2] = f2b(v0.z); d[3] = f2b(v0.w);
            d[4] = f2b(v1.x); d[5] = f2b(v1.y); d[6] = f2b(v1.z); d[7] = f2b(v1.w);
        }
        if (TRANS_B) {  // B stored (N,K): rows contiguous in k, same as A
            const int r = tid >> 2, ck = (tid & 3) << 3;
            const float* s = B + (long)(n0 + r) * ldb + k0 + ck;
            float4 v0 = *(const float4*)s, v1 = *(const float4*)(s + 4);
            unsigned short* d = &Bs[r][ck];
            d[0] = f2b(v0.x); d[1] = f2b(v0.y); d[2] = f2b(v0.z); d[3] = f2b(v0.w);
            d[4] = f2b(v1.x); d[5] = f2b(v1.y); d[6] = f2b(v1.z); d[7] = f2b(v1.w);
        } else {        // B stored (K,N): read rows of k, scatter-transpose into Bs[n][k]
            const int kk = tid >> 3, cn = (tid & 7) << 3;
            const float* s = B + (long)(k0 + kk) * ldb + n0 + cn;
            float4 v0 = *(const float4*)s, v1 = *(const float4*)(s + 4);
            Bs[cn + 0][kk] = f2b(v0.x); Bs[cn + 1][kk] = f2b(v0.y);
            Bs[cn + 2][kk] = f2b(v0.z); Bs[cn + 3][kk] = f2b(v0.w);
            Bs[cn + 4][kk] = f2b(v1.x); Bs[cn + 5][kk] = f2b(v1.y);
            Bs[cn + 6][kk] = f2b(v1.z); Bs[cn + 7][kk] = f2b(v1.w);
        }
        __syncthreads();
        // A-frag: lane holds A[m=lane&15][k=(lane>>4)*8+j]; B-frag symmetric.
        const int q8 = (lane >> 4) << 3;
        bf16x8 a0 = *(const bf16x8*)&As[wr +      (lane & 15)][q8];
        bf16x8 a1 = *(const bf16x8*)&As[wr + 16 + (lane & 15)][q8];
        bf16x8 b0 = *(const bf16x8*)&Bs[wc +      (lane & 15)][q8];
        bf16x8 b1 = *(const bf16x8*)&Bs[wc + 16 + (lane & 15)][q8];
        acc[0][0] = __builtin_amdgcn_mfma_f32_16x16x32_bf16(a0, b0, acc[0][0], 0, 0, 0);
        acc[0][1] = __builtin_amdgcn_mfma_f32_16x16x32_bf16(a0, b1, acc[0][1], 0, 0, 0);
        acc[1][0] = __builtin_amdgcn_mfma_f32_16x16x32_bf16(a1, b0, acc[1][0], 0, 0, 0);
        acc[1][1] = __builtin_amdgcn_mfma_f32_16x16x32_bf16(a1, b1, acc[1][1], 0, 0, 0);
        __syncthreads();
    }
    // Epilogue. D layout: col = lane&15, row = (lane>>4)*4 + reg.
    const int cq = lane >> 4, cc = lane & 15;
#pragma unroll
    for (int i = 0; i < 2; i++)
#pragma unroll
        for (int j = 0; j < 2; j++) {
#pragma unroll
            for (int rg = 0; rg < 4; rg++) {
                int row = m0 + wr + i * 16 + cq * 4 + rg;
                int col = n0 + wc + j * 16 + cc;
                float v = acc[i][j][rg];
                if (bias) v += bias[col];
                if (ACT == 1) v = v > 0.f ? v : 0.f;
                C[(long)row * ldc + col] = v;
            }
        }
}

// ---------------------------------------------------------------------------
// Helpers
// ---------------------------------------------------------------------------
__global__ void transpose_768(const float* __restrict__ src, float* __restrict__ dst)
{   // src (256,768) -> dst (768,256)
    int c = blockIdx.x, t = threadIdx.x;
    dst[(long)c * 256 + t] = src[(long)t * 768 + c];
}

__global__ void seq_major(const float* __restrict__ M, float* __restrict__ Mseq)
{   // M (n,s,256) -> Mseq (s,n,256)
    int b = blockIdx.x;               // s*256+n
    int s = b >> 8, n = b & 255;
    int t = threadIdx.x;
    Mseq[(long)b * 256 + t] = M[((long)n * 64 + s) * 256 + t];
}

__global__ void build_x(const float* __restrict__ values, const float* __restrict__ Mbuf,
                        const int* __restrict__ actions, const int* __restrict__ a0,
                        float* __restrict__ Xc, int t0)
{   // Xc row (tl*256+n) = [values[t,n,0:64], M[n, a_prev(t,n), 0:256]]
    int m = blockIdx.x;               // tl*256+n
    int tl = m >> 8, n = m & 255;
    int t = t0 + tl;
    int c = threadIdx.x;              // 0..319
    float v;
    if (c < 64) {
        v = values[((long)t * 256 + n) * 64 + c];
    } else {
        int ap = (t == 0) ? a0[n] : actions[(long)(t - 1) * 256 + n];
        v = Mbuf[((long)n * 64 + ap) * 256 + (c - 64)];
    }
    Xc[(long)m * 320 + c] = v;
}

// ---------------------------------------------------------------------------
// Bidirectional line-GRU scan over HR=64 rows. grid (64, 2): x = n-group of 4,
// y = dir (0 fw, 1 bw). Per-n recurrence is independent -> block-local only.
// ---------------------------------------------------------------------------
__global__ __launch_bounds__(256) void kgru_scan(
    const float* __restrict__ gfA, const float* __restrict__ gbA,
    const float* __restrict__ WTf, const float* __restrict__ WTb,
    const float* __restrict__ bhhf, const float* __restrict__ bhhb,
    float* __restrict__ Kbuf)
{
    __shared__ __align__(16) float hs[4][256];
    const int t = threadIdx.x;
    const int bx = blockIdx.x;
    const int d = blockIdx.y;
    const float* gi_all = d ? gbA : gfA;
    const float* WT  = d ? WTb : WTf;
    const float* bhh = d ? bhhb : bhhf;
#pragma unroll
    for (int r = 0; r < 4; r++) hs[r][t] = 0.f;
    __syncthreads();
    const float b0 = bhh[t], b1 = bhh[t + 256], b2 = bhh[t + 512];
    const float* w0 = WT + (long)t * 256;
    const float* w1 = WT + (long)(t + 256) * 256;
    const float* w2 = WT + (long)(t + 512) * 256;
    for (int i = 0; i < 64; i++) {
        float a0[4], a1[4], a2[4];
#pragma unroll
        for (int r = 0; r < 4; r++) { a0[r] = b0; a1[r] = b1; a2[r] = b2; }
        for (int k = 0; k < 256; k += 16) {
            float4 v0[4], v1[4], v2[4];
#pragma unroll
            for (int u = 0; u < 4; u++) {
                v0[u] = *(const float4*)(w0 + k + 4 * u);
                v1[u] = *(const float4*)(w1 + k + 4 * u);
                v2[u] = *(const float4*)(w2 + k + 4 * u);
            }
#pragma unroll
            for (int r = 0; r < 4; r++) {
#pragma unroll
                for (int u = 0; u < 4; u++) {
                    float4 hv = *(const float4*)&hs[r][k + 4 * u];
                    a0[r] += hv.x * v0[u].x + hv.y * v0[u].y + hv.z * v0[u].z + hv.w * v0[u].w;
                    a1[r] += hv.x * v1[u].x + hv.y * v1[u].y + hv.z * v1[u].z + hv.w * v1[u].w;
                    a2[r] += hv.x * v2[u].x + hv.y * v2[u].y + hv.z * v2[u].z + hv.w * v2[u].w;
                }
            }
        }
        int row = d ? (63 - i) : i;   // gi row and output row coincide
        float hn[4];
#pragma unroll
        for (int r = 0; r < 4; r++) {
            int n = bx * 4 + r;
            long g = ((long)row * 256 + n) * 768;
            float ir = gi_all[g + t], iz = gi_all[g + 256 + t], in_ = gi_all[g + 512 + t];
            float rg = sigmoidf_(ir + a0[r]);
            float zg = sigmoidf_(iz + a1[r]);
            float ng = tanhf_(in_ + rg * a2[r]);
            hn[r] = (1.f - zg) * ng + zg * hs[r][t];
        }
        __syncthreads();
#pragma unroll
        for (int r = 0; r < 4; r++) {
            hs[r][t] = hn[r];
            int n = bx * 4 + r;
            Kbuf[((long)n * 64 + row) * 512 + d * 256 + t] = hn[r];
        }
        __syncthreads();
    }
}

// ---------------------------------------------------------------------------
// Main cell-GRU scan, one chunk of TCHUNK steps. grid 64 blocks x 4 rows.
// ---------------------------------------------------------------------------
__global__ __launch_bounds__(256) void main_scan(
    const float* __restrict__ GIc,     // (TCHUNK*256, 768)
    const float* __restrict__ WT,      // cell_Whh^T (768,256)
    const float* __restrict__ bhh,     // 768
    const float* __restrict__ h_init,  // (256,256)
    float* __restrict__ h_state,       // (256,256)
    float* __restrict__ Hallc)         // (TCHUNK*256, 256)
{
    __shared__ __align__(16) float hs[4][256];
    const int t = threadIdx.x;
    const int bx = blockIdx.x;
#pragma unroll
    for (int r = 0; r < 4; r++) hs[r][t] = h_init[((long)bx * 4 + r) * 256 + t];
    __syncthreads();
    const float b0 = bhh[t], b1 = bhh[t + 256], b2 = bhh[t + 512];
    const float* w0 = WT + (long)t * 256;
    const float* w1 = WT + (long)(t + 256) * 256;
    const float* w2 = WT + (long)(t + 512) * 256;
    for (int step = 0; step < TCHUNK; step++) {
        float a0[4], a1[4], a2[4];
#pragma unroll
        for (int r = 0; r < 4; r++) { a0[r] = b0; a1[r] = b1; a2[r] = b2; }
        for (int k = 0; k < 256; k += 16) {
            float4 v0[4], v1[4], v2[4];
#pragma unroll
            for (int u = 0; u < 4; u++) {
                v0[u] = *(const float4*)(w0 + k + 4 * u);
                v1[u] = *(const float4*)(w1 + k + 4 * u);
                v2[u] = *(const float4*)(w2 + k + 4 * u);
            }
#pragma unroll
            for (int r = 0; r < 4; r++) {
#pragma unroll
                for (int u = 0; u < 4; u++) {
                    float4 hv = *(const float4*)&hs[r][k + 4 * u];
                    a0[r] += hv.x * v0[u].x + hv.y * v0[u].y + hv.z * v0[u].z + hv.w * v0[u].w;
                    a1[r] += hv.x * v1[u].x + hv.y * v1[u].y + hv.z * v1[u].z + hv.w * v1[u].w;
                    a2[r] += hv.x * v2[u].x + hv.y * v2[u].y + hv.z * v2[u].z + hv.w * v2[u].w;
                }
            }
        }
        float hn[4];
#pragma unroll
        for (int r = 0; r < 4; r++) {
            int n = bx * 4 + r;
            long g = ((long)step * 256 + n) * 768;
            float ir = GIc[g + t], iz = GIc[g + 256 + t], in_ = GIc[g + 512 + t];
            float rg = sigmoidf_(ir + a0[r]);
            float zg = sigmoidf_(iz + a1[r]);
            float ng = tanhf_(in_ + rg * a2[r]);
            hn[r] = (1.f - zg) * ng + zg * hs[r][t];
        }
        __syncthreads();
#pragma unroll
        for (int r = 0; r < 4; r++) {
            hs[r][t] = hn[r];
            Hallc[((long)step * 256 + bx * 4 + r) * 256 + t] = hn[r];
        }
        __syncthreads();
    }
#pragma unroll
    for (int r = 0; r < 4; r++) h_state[((long)bx * 4 + r) * 256 + t] = hs[r][t];
}

// ---------------------------------------------------------------------------
// Epilogue: per (t,n) write a, v=critic(h), h copy, softmax(logits).
// grid TCHUNK*256 blocks x 64 threads (1 wave).
// ---------------------------------------------------------------------------
__global__ __launch_bounds__(64) void epilogue_k(
    const float* __restrict__ Hallc, const float* __restrict__ Lc,
    const int* __restrict__ actions,
    const float* __restrict__ critic_W, const float* __restrict__ critic_b,
    float* __restrict__ out, int t0)
{
    int m = blockIdx.x;               // tl*256+n
    int tl = m >> 8, n = m & 255;
    int t = t0 + tl;
    int j = threadIdx.x;              // 0..63
    long o = ((long)t * 256 + n) * 322;
    const float* h = Hallc + (long)m * 256;
    float part = 0.f;
#pragma unroll
    for (int i = 0; i < 4; i++) {
        float hv = h[j + 64 * i];
        out[o + 2 + j + 64 * i] = hv;
        part += hv * critic_W[j + 64 * i];
    }
    for (int off = 32; off > 0; off >>= 1) part += __shfl_down(part, off);
    if (j == 0) {
        out[o]     = (float)actions[(long)t * 256 + n];
        out[o + 1] = part + critic_b[0];
    }
    float x = Lc[(long)m * 64 + j];
    float mx = x;
    for (int off = 32; off > 0; off >>= 1) mx = fmaxf(mx, __shfl_down(mx, off));
    mx = __shfl(mx, 0);
    float e = __expf(x - mx);
    float ssum = e;
    for (int off = 32; off > 0; off >>= 1) ssum += __shfl_down(ssum, off);
    ssum = __shfl(ssum, 0);
    out[o + 258 + j] = e / ssum;
}

// ---------------------------------------------------------------------------
extern "C" void kernel_launch(void* const* d_in, const int* in_sizes, int n_in,
                              void* d_out, int out_size, void* d_ws, size_t ws_size,
                              hipStream_t stream)
{
    const float* values   = (const float*)d_in[0];
    const float* mdp      = (const float*)d_in[1];
    const int*   actions  = (const int*)  d_in[2];
    const int*   a0       = (const int*)  d_in[3];
    const float* h0       = (const float*)d_in[4];
    const float* emb_W    = (const float*)d_in[5];
    const float* emb_b    = (const float*)d_in[6];
    const float* gfw_Wih  = (const float*)d_in[7];
    const float* gfw_Whh  = (const float*)d_in[8];
    const float* gfw_bih  = (const float*)d_in[9];
    const float* gfw_bhh  = (const float*)d_in[10];
    const float* gbw_Wih  = (const float*)d_in[11];
    const float* gbw_Whh  = (const float*)d_in[12];
    const float* gbw_bih  = (const float*)d_in[13];
    const float* gbw_bhh  = (const float*)d_in[14];
    const float* f0_W     = (const float*)d_in[15];
    const float* f0_b     = (const float*)d_in[16];
    const float* f1_W     = (const float*)d_in[17];
    const float* f1_b     = (const float*)d_in[18];
    const float* cell_Wih = (const float*)d_in[19];
    const float* cell_Whh = (const float*)d_in[20];
    const float* cell_bih = (const float*)d_in[21];
    const float* cell_bhh = (const float*)d_in[22];
    const float* critic_W = (const float*)d_in[23];
    const float* critic_b = (const float*)d_in[24];
    const float* qg_W     = (const float*)d_in[25];
    const float* qg_b     = (const float*)d_in[26];
    float* out = (float*)d_out;

    // workspace arena (~330 MB)
    char* base = (char*)d_ws;
    size_t off = 0;
    auto alloc = [&](size_t nf) -> float* {
        float* p = (float*)(base + off);
        off += nf * sizeof(float);
        off = (off + 255) & ~(size_t)255;
        return p;
    };
    float* Mbuf   = alloc(16384ull * 256);   // (n,s,H) line embeddings
    float* Mseq   = alloc(16384ull * 256);   // (s,n,H)
    float* gfA    = alloc(16384ull * 768);   // fw gate inputs
    float* gbA    = alloc(16384ull * 768);   // bw gate inputs (forward s order)
    float* Kbuf   = alloc(256ull * 64 * 512);// K (n, s, 2H)
    float* WTf    = alloc(768ull * 256);
    float* WTb    = alloc(768ull * 256);
    float* WTc    = alloc(768ull * 256);
    float* hstate = alloc(256ull * 256);
    float* Xc     = alloc(16384ull * 320);
    float* X0c    = alloc(16384ull * 256);
    float* X1c    = alloc(16384ull * 256);
    float* GIc    = alloc(16384ull * 768);
    float* Qc     = alloc(16384ull * 512);
    float* Lc     = alloc(16384ull * 64);
    float* Hallc  = alloc(16384ull * 256);
    (void)ws_size; (void)in_sizes; (void)n_in; (void)out_size;

    dim3 blk(256);

    // Phase 1: embeddings + line-GRU gate inputs + weight transposes
    gemm_f32<false, 0><<<dim3(4, 256, 1), blk, 0, stream>>>(
        mdp, 128, 0, emb_W, 256, 0, emb_b, Mbuf, 256, 0, 16384, 256, 128);
    seq_major<<<dim3(16384), blk, 0, stream>>>(Mbuf, Mseq);
    transpose_768<<<dim3(768), blk, 0, stream>>>(gfw_Whh, WTf);
    transpose_768<<<dim3(768), blk, 0, stream>>>(gbw_Whh, WTb);
    transpose_768<<<dim3(768), blk, 0, stream>>>(cell_Whh, WTc);
    gemm_f32<false, 0><<<dim3(12, 256, 1), blk, 0, stream>>>(
        Mseq, 256, 0, gfw_Wih, 768, 0, gfw_bih, gfA, 768, 0, 16384, 768, 256);
    gemm_f32<false, 0><<<dim3(12, 256, 1), blk, 0, stream>>>(
        Mseq, 256, 0, gbw_Wih, 768, 0, gbw_bih, gbA, 768, 0, 16384, 768, 256);
    kgru_scan<<<dim3(64, 2, 1), blk, 0, stream>>>(gfA, gbA, WTf, WTb, gfw_bhh, gbw_bhh, Kbuf);

    // Phase 2/3: chunked x-path GEMMs -> scan -> query/logits/epilogue
    for (int c = 0; c < NCHUNK; c++) {
        int t0 = c * TCHUNK;
        build_x<<<dim3(16384), dim3(320), 0, stream>>>(values, Mbuf, actions, a0, Xc, t0);
        gemm_f32<false, 1><<<dim3(4, 256, 1), blk, 0, stream>>>(
            Xc, 320, 0, f0_W, 256, 0, f0_b, X0c, 256, 0, 16384, 256, 320);
        gemm_f32<false, 1><<<dim3(4, 256, 1), blk, 0, stream>>>(
            X0c, 256, 0, f1_W, 256, 0, f1_b, X1c, 256, 0, 16384, 256, 256);
        gemm_f32<false, 0><<<dim3(12, 256, 1), blk, 0, stream>>>(
            X1c, 256, 0, cell_Wih, 768, 0, cell_bih, GIc, 768, 0, 16384, 768, 256);
        main_scan<<<dim3(64), blk, 0, stream>>>(
            GIc, WTc, cell_bhh, (c == 0) ? h0 : (const float*)hstate, hstate, Hallc);
        gemm_f32<false, 0><<<dim3(8, 256, 1), blk, 0, stream>>>(
            Hallc, 256, 0, qg_W, 512, 0, qg_b, Qc, 512, 0, 16384, 512, 256);
        // logits: batched over n. A = Qc rows (tl) for batch n, B = K[n] (64,512) transposed.
        gemm_f32<true, 0><<<dim3(1, 1, 256), blk, 0, stream>>>(
            Qc, 131072, 512, Kbuf, 512, 32768, nullptr, Lc, 16384, 64, 64, 64, 512);
        epilogue_k<<<dim3(16384), dim3(64), 0, stream>>>(
            Hallc, Lc, actions, critic_W, critic_b, out, t0);
    }
}

// Round 2
// 4898.998 us; speedup vs baseline: 3.2450x; 3.2450x over previous
//
#include <hip/hip_runtime.h>

// Problem constants (reference: T=512, N=256, H=256, HR=64, WC=128, V=64)
#define TSTEPS 512
#define NBATCH 256
#define HID    256
#define TCHUNK 64
#define NCHUNK 8

typedef __attribute__((ext_vector_type(8))) short bf16x8;
typedef __attribute__((ext_vector_type(4))) float f32x4;

__device__ __forceinline__ unsigned short f2b(float x) {
    union { float f; unsigned int u; } c; c.f = x;
    unsigned int u = c.u;
    return (unsigned short)((u + 0x7fffu + ((u >> 16) & 1u)) >> 16);
}
__device__ __forceinline__ float sigmoidf_(float x) { return 1.f / (1.f + __expf(-x)); }
__device__ __forceinline__ float tanhf_(float x)    { return 1.f - 2.f / (1.f + __expf(2.f * x)); }

__device__ __forceinline__ void gload_lds16(const float* g, float* l) {
    __builtin_amdgcn_global_load_lds(
        (const __attribute__((address_space(1))) unsigned int*)g,
        (__attribute__((address_space(3))) unsigned int*)l,
        16, 0, 0);
}

// ---------------------------------------------------------------------------
// Generic GEMM: C[M,N] = act(A[M,K] @ B + bias), bf16 MFMA, fp32 in/out.
// (unchanged from round 0 — verified correct)
// ---------------------------------------------------------------------------
template<bool TRANS_B, int ACT>
__global__ __launch_bounds__(256) void gemm_f32(
    const float* __restrict__ A, long lda, long sA,
    const float* __restrict__ B, long ldb, long sB,
    const float* __restrict__ bias,
    float* __restrict__ C, long ldc, long sC,
    int M, int N, int K)
{
    __shared__ __align__(16) unsigned short As[64][32];  // [m][k] bf16
    __shared__ __align__(16) unsigned short Bs[64][32];  // [n][k] bf16
    const int z = blockIdx.z;
    A += (long)z * sA; B += (long)z * sB; C += (long)z * sC;
    const int n0 = blockIdx.x * 64, m0 = blockIdx.y * 64;
    const int tid  = threadIdx.x;
    const int lane = tid & 63, w = tid >> 6;
    const int wr = (w >> 1) * 32, wc = (w & 1) * 32;

    f32x4 acc[2][2];
#pragma unroll
    for (int i = 0; i < 2; i++)
#pragma unroll
        for (int j = 0; j < 2; j++) acc[i][j] = (f32x4){0.f, 0.f, 0.f, 0.f};

    for (int k0 = 0; k0 < K; k0 += 32) {
        {   // stage A tile: 64 rows x 32 k
            const int r = tid >> 2, ck = (tid & 3) << 3;
            const float* s = A + (long)(m0 + r) * lda + k0 + ck;
            float4 v0 = *(const float4*)s, v1 = *(const float4*)(s + 4);
            unsigned short* d = &As[r][ck];
            d[0] = f2b(v0.x); d[1] = f2b(v0.y); d[2] = f2b(v0.z); d[3] = f2b(v0.w);
            d[4] = f2b(v1.x); d[5] = f2b(v1.y); d[6] = f2b(v1.z); d[7] = f2b(v1.w);
        }
        if (TRANS_B) {  // B stored (N,K)
            const int r = tid >> 2, ck = (tid & 3) << 3;
            const float* s = B + (long)(n0 + r) * ldb + k0 + ck;
            float4 v0 = *(const float4*)s, v1 = *(const float4*)(s + 4);
            unsigned short* d = &Bs[r][ck];
            d[0] = f2b(v0.x); d[1] = f2b(v0.y); d[2] = f2b(v0.z); d[3] = f2b(v0.w);
            d[4] = f2b(v1.x); d[5] = f2b(v1.y); d[6] = f2b(v1.z); d[7] = f2b(v1.w);
        } else {        // B stored (K,N): scatter-transpose
            const int kk = tid >> 3, cn = (tid & 7) << 3;
            const float* s = B + (long)(k0 + kk) * ldb + n0 + cn;
            float4 v0 = *(const float4*)s, v1 = *(const float4*)(s + 4);
            Bs[cn + 0][kk] = f2b(v0.x); Bs[cn + 1][kk] = f2b(v0.y);
            Bs[cn + 2][kk] = f2b(v0.z); Bs[cn + 3][kk] = f2b(v0.w);
            Bs[cn + 4][kk] = f2b(v1.x); Bs[cn + 5][kk] = f2b(v1.y);
            Bs[cn + 6][kk] = f2b(v1.z); Bs[cn + 7][kk] = f2b(v1.w);
        }
        __syncthreads();
        const int q8 = (lane >> 4) << 3;
        bf16x8 a0 = *(const bf16x8*)&As[wr +      (lane & 15)][q8];
        bf16x8 a1 = *(const bf16x8*)&As[wr + 16 + (lane & 15)][q8];
        bf16x8 b0 = *(const bf16x8*)&Bs[wc +      (lane & 15)][q8];
        bf16x8 b1 = *(const bf16x8*)&Bs[wc + 16 + (lane & 15)][q8];
        acc[0][0] = __builtin_amdgcn_mfma_f32_16x16x32_bf16(a0, b0, acc[0][0], 0, 0, 0);
        acc[0][1] = __builtin_amdgcn_mfma_f32_16x16x32_bf16(a0, b1, acc[0][1], 0, 0, 0);
        acc[1][0] = __builtin_amdgcn_mfma_f32_16x16x32_bf16(a1, b0, acc[1][0], 0, 0, 0);
        acc[1][1] = __builtin_amdgcn_mfma_f32_16x16x32_bf16(a1, b1, acc[1][1], 0, 0, 0);
        __syncthreads();
    }
    const int cq = lane >> 4, cc = lane & 15;
#pragma unroll
    for (int i = 0; i < 2; i++)
#pragma unroll
        for (int j = 0; j < 2; j++) {
#pragma unroll
            for (int rg = 0; rg < 4; rg++) {
                int row = m0 + wr + i * 16 + cq * 4 + rg;
                int col = n0 + wc + j * 16 + cc;
                float v = acc[i][j][rg];
                if (bias) v += bias[col];
                if (ACT == 1) v = v > 0.f ? v : 0.f;
                C[(long)row * ldc + col] = v;
            }
        }
}

// ---------------------------------------------------------------------------
// Helpers
// ---------------------------------------------------------------------------
__global__ void transpose_768(const float* __restrict__ src, float* __restrict__ dst)
{   // src (256,768) -> dst (768,256)
    int c = blockIdx.x, t = threadIdx.x;
    dst[(long)c * 256 + t] = src[(long)t * 768 + c];
}

__global__ void combine_bias(const float* a0, const float* b0,
                             const float* a1, const float* b1,
                             const float* a2, const float* b2,
                             float* o0, float* o1, float* o2)
{
    int i = blockIdx.x * 256 + threadIdx.x;   // 0..767
    o0[i] = a0[i] + b0[i];
    o1[i] = a1[i] + b1[i];
    o2[i] = a2[i] + b2[i];
}

__global__ void seq_major(const float* __restrict__ M, float* __restrict__ Mseq)
{   // M (n,s,256) -> Mseq (s,n,256)
    int b = blockIdx.x;               // s*256+n
    int s = b >> 8, n = b & 255;
    int t = threadIdx.x;
    Mseq[(long)b * 256 + t] = M[((long)n * 64 + s) * 256 + t];
}

__global__ void build_x(const float* __restrict__ values, const float* __restrict__ Mbuf,
                        const int* __restrict__ actions, const int* __restrict__ a0,
                        float* __restrict__ Xc, int t0)
{   // Xc row (tl*256+n) = [values[t,n,0:64], M[n, a_prev(t,n), 0:256]]
    int m = blockIdx.x;               // tl*256+n
    int tl = m >> 8, n = m & 255;
    int t = t0 + tl;
    int c = threadIdx.x;              // 0..319
    float v;
    if (c < 64) {
        v = values[((long)t * 256 + n) * 64 + c];
    } else {
        int ap = (t == 0) ? a0[n] : actions[(long)(t - 1) * 256 + n];
        v = Mbuf[((long)n * 64 + ap) * 256 + (c - 64)];
    }
    Xc[(long)m * 320 + c] = v;
}

// ---------------------------------------------------------------------------
// Weight-stationary MFMA GRU scan. 16 n-rows per block, 256 threads (4 waves,
// 1 wave/SIMD, 512-VGPR budget). Wave w owns h-cols [w*64,(w+1)*64) and the
// matching 3x64 gate columns; full Whh^T lives in 96 bf16x8 B-frags (384 VGPR).
// h stays in registers in MFMA C-layout; bf16 copy staged via LDS (stride 264,
// conflict-free ds_read_b128) for next step's A-frags. Gate inputs gi (bias
// pre-folded) prefetched one step ahead via global_load_lds into one LDS
// buffer (issue after B2, drained at next B1). Two barriers per step.
// ---------------------------------------------------------------------------
template<int KGRU>
__global__ __launch_bounds__(256, 1) void scan_mfma(
    const float* __restrict__ gi0, const float* __restrict__ gi1,
    const float* __restrict__ WT0, const float* __restrict__ WT1,
    const float* __restrict__ h_init,   // null-equivalent for KGRU (zeros)
    float* __restrict__ outp,           // main: Hallc ; kgru: Kbuf
    float* __restrict__ h_state,        // main only
    int steps)
{
    __shared__ __align__(16) unsigned short hstage[16][264];
    __shared__ __align__(16) float gi_lds[16 * 772];

    const int tid = threadIdx.x;
    const int w = tid >> 6, lane = tid & 63;
    const int q = lane >> 4, c = lane & 15, q8 = q << 3;
    const int n0 = blockIdx.x * 16;
    const int d = KGRU ? blockIdx.y : 0;
    const float* gi = d ? gi1 : gi0;
    const float* WT = d ? WT1 : WT0;

    // ---- one-time: weight B-fragments (wave w -> gate cols g*256+w*64+hh*16) ----
    bf16x8 Bf[12][8];
#pragma unroll
    for (int g = 0; g < 3; g++)
#pragma unroll
        for (int hh = 0; hh < 4; hh++) {
            const float* src = WT + (long)(g * 256 + w * 64 + hh * 16 + c) * 256;
#pragma unroll
            for (int kt = 0; kt < 8; kt++) {
                const float* s8 = src + kt * 32 + q8;
                float4 u0 = *(const float4*)s8, u1 = *(const float4*)(s8 + 4);
                bf16x8 b;
                b[0] = (short)f2b(u0.x); b[1] = (short)f2b(u0.y);
                b[2] = (short)f2b(u0.z); b[3] = (short)f2b(u0.w);
                b[4] = (short)f2b(u1.x); b[5] = (short)f2b(u1.y);
                b[6] = (short)f2b(u1.z); b[7] = (short)f2b(u1.w);
                Bf[g * 4 + hh][kt] = b;
            }
        }

    // ---- h init: registers (C-layout) + bf16 staging ----
    f32x4 hreg[4];
#pragma unroll
    for (int hh = 0; hh < 4; hh++)
#pragma unroll
        for (int rg = 0; rg < 4; rg++) {
            float v = 0.f;
            if (!KGRU) v = h_init[(long)(n0 + q * 4 + rg) * 256 + w * 64 + hh * 16 + c];
            hreg[hh][rg] = v;
            hstage[q * 4 + rg][w * 64 + hh * 16 + c] = f2b(v);
        }

    // ---- issue gi prefetch for step 0 (16 rows x 768 f32 = 48 x 1024B) ----
    {
        int row0 = KGRU ? (d ? 63 : 0) : 0;
        const float* src = gi + ((long)row0 * 256 + n0) * 768;
#pragma unroll
        for (int rr = 0; rr < 4; rr++)
#pragma unroll
            for (int ch = 0; ch < 3; ch++) {
                const float* gsrc = src + (w * 4 + rr) * 768 + ch * 256 + lane * 4;
                float* ldst = &gi_lds[(w * 4 + rr) * 772 + ch * 256];
                gload_lds16(gsrc, ldst);
            }
    }
    __syncthreads();

    for (int s = 0; s < steps; s++) {
        // ---- gh = h(s-1) @ Whh : 96 mfma, weight-stationary ----
        f32x4 acc[12];
#pragma unroll
        for (int t = 0; t < 12; t++) acc[t] = (f32x4){0.f, 0.f, 0.f, 0.f};
#pragma unroll
        for (int kt = 0; kt < 8; kt++) {
            bf16x8 a = *(const bf16x8*)&hstage[c][kt * 32 + q8];
#pragma unroll
            for (int t = 0; t < 12; t++)
                acc[t] = __builtin_amdgcn_mfma_f32_16x16x32_bf16(a, Bf[t][kt], acc[t], 0, 0, 0);
        }
        __syncthreads();   // B1: hstage reads done; gi(s) load drained (vmcnt0@barrier)

        const int out_row = KGRU ? (d ? (63 - s) : s) : s;

        // ---- gates + state update (h_old lives in regs, same layout) ----
#pragma unroll
        for (int hh = 0; hh < 4; hh++) {
            f32x4 hn;
#pragma unroll
            for (int rg = 0; rg < 4; rg++) {
                int lrow = q * 4 + rg;
                int col = w * 64 + hh * 16 + c;
                float gr = gi_lds[lrow * 772 +       col];
                float gz = gi_lds[lrow * 772 + 256 + col];
                float gn = gi_lds[lrow * 772 + 512 + col];
                float r  = sigmoidf_(gr + acc[0 * 4 + hh][rg]);
                float zg = sigmoidf_(gz + acc[1 * 4 + hh][rg]);
                float nn = tanhf_(gn + r * acc[2 * 4 + hh][rg]);
                hn[rg] = (1.f - zg) * nn + zg * hreg[hh][rg];
            }
            hreg[hh] = hn;
        }

        // ---- stage h(s) bf16 + store fp32 output ----
#pragma unroll
        for (int hh = 0; hh < 4; hh++)
#pragma unroll
            for (int rg = 0; rg < 4; rg++) {
                int lrow = q * 4 + rg;
                int col = w * 64 + hh * 16 + c;
                float v = hreg[hh][rg];
                hstage[lrow][col] = f2b(v);
                if (KGRU)
                    outp[((long)(n0 + lrow) * 64 + out_row) * 512 + d * 256 + col] = v;
                else
                    outp[((long)s * 256 + n0 + lrow) * 256 + col] = v;
            }
        __syncthreads();   // B2: hstage writes visible; gi_lds reads done

        // ---- issue gi prefetch for step s+1 ----
        if (s + 1 < steps) {
            int rown = KGRU ? (d ? (63 - (s + 1)) : (s + 1)) : (s + 1);
            const float* src = gi + ((long)rown * 256 + n0) * 768;
#pragma unroll
            for (int rr = 0; rr < 4; rr++)
#pragma unroll
                for (int ch = 0; ch < 3; ch++) {
                    const float* gsrc = src + (w * 4 + rr) * 768 + ch * 256 + lane * 4;
                    float* ldst = &gi_lds[(w * 4 + rr) * 772 + ch * 256];
                    gload_lds16(gsrc, ldst);
                }
        }
    }

    if (!KGRU) {
#pragma unroll
        for (int hh = 0; hh < 4; hh++)
#pragma unroll
            for (int rg = 0; rg < 4; rg++)
                h_state[(long)(n0 + q * 4 + rg) * 256 + w * 64 + hh * 16 + c] = hreg[hh][rg];
    }
}

// ---------------------------------------------------------------------------
// Epilogue: per (t,n) write a, v=critic(h), h copy, softmax(logits).
// ---------------------------------------------------------------------------
__global__ __launch_bounds__(64) void epilogue_k(
    const float* __restrict__ Hallc, const float* __restrict__ Lc,
    const int* __restrict__ actions,
    const float* __restrict__ critic_W, const float* __restrict__ critic_b,
    float* __restrict__ out, int t0)
{
    int m = blockIdx.x;               // tl*256+n
    int tl = m >> 8, n = m & 255;
    int t = t0 + tl;
    int j = threadIdx.x;              // 0..63
    long o = ((long)t * 256 + n) * 322;
    const float* h = Hallc + (long)m * 256;
    float part = 0.f;
#pragma unroll
    for (int i = 0; i < 4; i++) {
        float hv = h[j + 64 * i];
        out[o + 2 + j + 64 * i] = hv;
        part += hv * critic_W[j + 64 * i];
    }
    for (int off = 32; off > 0; off >>= 1) part += __shfl_down(part, off);
    if (j == 0) {
        out[o]     = (float)actions[(long)t * 256 + n];
        out[o + 1] = part + critic_b[0];
    }
    float x = Lc[(long)m * 64 + j];
    float mx = x;
    for (int off = 32; off > 0; off >>= 1) mx = fmaxf(mx, __shfl_down(mx, off));
    mx = __shfl(mx, 0);
    float e = __expf(x - mx);
    float ssum = e;
    for (int off = 32; off > 0; off >>= 1) ssum += __shfl_down(ssum, off);
    ssum = __shfl(ssum, 0);
    out[o + 258 + j] = e / ssum;
}

// ---------------------------------------------------------------------------
extern "C" void kernel_launch(void* const* d_in, const int* in_sizes, int n_in,
                              void* d_out, int out_size, void* d_ws, size_t ws_size,
                              hipStream_t stream)
{
    const float* values   = (const float*)d_in[0];
    const float* mdp      = (const float*)d_in[1];
    const int*   actions  = (const int*)  d_in[2];
    const int*   a0       = (const int*)  d_in[3];
    const float* h0       = (const float*)d_in[4];
    const float* emb_W    = (const float*)d_in[5];
    const float* emb_b    = (const float*)d_in[6];
    const float* gfw_Wih  = (const float*)d_in[7];
    const float* gfw_Whh  = (const float*)d_in[8];
    const float* gfw_bih  = (const float*)d_in[9];
    const float* gfw_bhh  = (const float*)d_in[10];
    const float* gbw_Wih  = (const float*)d_in[11];
    const float* gbw_Whh  = (const float*)d_in[12];
    const float* gbw_bih  = (const float*)d_in[13];
    const float* gbw_bhh  = (const float*)d_in[14];
    const float* f0_W     = (const float*)d_in[15];
    const float* f0_b     = (const float*)d_in[16];
    const float* f1_W     = (const float*)d_in[17];
    const float* f1_b     = (const float*)d_in[18];
    const float* cell_Wih = (const float*)d_in[19];
    const float* cell_Whh = (const float*)d_in[20];
    const float* cell_bih = (const float*)d_in[21];
    const float* cell_bhh = (const float*)d_in[22];
    const float* critic_W = (const float*)d_in[23];
    const float* critic_b = (const float*)d_in[24];
    const float* qg_W     = (const float*)d_in[25];
    const float* qg_b     = (const float*)d_in[26];
    float* out = (float*)d_out;

    char* base = (char*)d_ws;
    size_t off = 0;
    auto alloc = [&](size_t nf) -> float* {
        float* p = (float*)(base + off);
        off += nf * sizeof(float);
        off = (off + 255) & ~(size_t)255;
        return p;
    };
    float* Mbuf   = alloc(16384ull * 256);   // (n,s,H) line embeddings
    float* Mseq   = alloc(16384ull * 256);   // (s,n,H)
    float* gfA    = alloc(16384ull * 768);   // fw gate inputs (bias folded)
    float* gbA    = alloc(16384ull * 768);   // bw gate inputs (bias folded)
    float* Kbuf   = alloc(256ull * 64 * 512);// K (n, s, 2H)
    float* WTf    = alloc(768ull * 256);
    float* WTb    = alloc(768ull * 256);
    float* WTc    = alloc(768ull * 256);
    float* hstate = alloc(256ull * 256);
    float* Xc     = alloc(16384ull * 320);
    float* X0c    = alloc(16384ull * 256);
    float* X1c    = alloc(16384ull * 256);
    float* GIc    = alloc(16384ull * 768);
    float* Qc     = alloc(16384ull * 512);
    float* Lc     = alloc(16384ull * 64);
    float* Hallc  = alloc(16384ull * 256);
    float* bias_f = alloc(768);
    float* bias_b = alloc(768);
    float* bias_c = alloc(768);
    (void)ws_size; (void)in_sizes; (void)n_in; (void)out_size;

    dim3 blk(256);

    // Phase 1: embeddings + line-GRU gate inputs + weight prep
    gemm_f32<false, 0><<<dim3(4, 256, 1), blk, 0, stream>>>(
        mdp, 128, 0, emb_W, 256, 0, emb_b, Mbuf, 256, 0, 16384, 256, 128);
    seq_major<<<dim3(16384), blk, 0, stream>>>(Mbuf, Mseq);
    transpose_768<<<dim3(768), blk, 0, stream>>>(gfw_Whh, WTf);
    transpose_768<<<dim3(768), blk, 0, stream>>>(gbw_Whh, WTb);
    transpose_768<<<dim3(768), blk, 0, stream>>>(cell_Whh, WTc);
    combine_bias<<<dim3(3), blk, 0, stream>>>(gfw_bih, gfw_bhh, gbw_bih, gbw_bhh,
                                              cell_bih, cell_bhh, bias_f, bias_b, bias_c);
    gemm_f32<false, 0><<<dim3(12, 256, 1), blk, 0, stream>>>(
        Mseq, 256, 0, gfw_Wih, 768, 0, bias_f, gfA, 768, 0, 16384, 768, 256);
    gemm_f32<false, 0><<<dim3(12, 256, 1), blk, 0, stream>>>(
        Mseq, 256, 0, gbw_Wih, 768, 0, bias_b, gbA, 768, 0, 16384, 768, 256);
    scan_mfma<1><<<dim3(16, 2, 1), blk, 0, stream>>>(
        gfA, gbA, WTf, WTb, nullptr, Kbuf, nullptr, 64);

    // Phase 2/3: chunked x-path GEMMs -> scan -> query/logits/epilogue
    for (int c = 0; c < NCHUNK; c++) {
        int t0 = c * TCHUNK;
        build_x<<<dim3(16384), dim3(320), 0, stream>>>(values, Mbuf, actions, a0, Xc, t0);
        gemm_f32<false, 1><<<dim3(4, 256, 1), blk, 0, stream>>>(
            Xc, 320, 0, f0_W, 256, 0, f0_b, X0c, 256, 0, 16384, 256, 320);
        gemm_f32<false, 1><<<dim3(4, 256, 1), blk, 0, stream>>>(
            X0c, 256, 0, f1_W, 256, 0, f1_b, X1c, 256, 0, 16384, 256, 256);
        gemm_f32<false, 0><<<dim3(12, 256, 1), blk, 0, stream>>>(
            X1c, 256, 0, cell_Wih, 768, 0, bias_c, GIc, 768, 0, 16384, 768, 256);
        scan_mfma<0><<<dim3(16, 1, 1), blk, 0, stream>>>(
            GIc, nullptr, WTc, nullptr, (c == 0) ? h0 : (const float*)hstate,
            Hallc, hstate, TCHUNK);
        gemm_f32<false, 0><<<dim3(8, 256, 1), blk, 0, stream>>>(
            Hallc, 256, 0, qg_W, 512, 0, qg_b, Qc, 512, 0, 16384, 512, 256);
        gemm_f32<true, 0><<<dim3(1, 1, 256), blk, 0, stream>>>(
            Qc, 131072, 512, Kbuf, 512, 32768, nullptr, Lc, 16384, 64, 64, 64, 512);
        epilogue_k<<<dim3(16384), dim3(64), 0, stream>>>(
            Hallc, Lc, actions, critic_W, critic_b, out, t0);
    }
}